// Round 5
// baseline (157.838 us; speedup 1.0000x reference)
//
#include <hip/hip_runtime.h>
#include <math.h>

#define DK 32
#define OUT_DIM 32
#define NODES_PER_WAVE 4

// Fill row_ptr[0..N] such that row_ptr[n] = first edge index with dst >= n.
__global__ void build_row_ptr_kernel(const int* __restrict__ dst, int E, int N,
                                     int* __restrict__ row_ptr) {
    int e = blockIdx.x * blockDim.x + threadIdx.x;
    if (e >= E) return;
    int cur  = dst[e];
    int prev = (e == 0) ? -1 : dst[e - 1];
    for (int j = prev + 1; j <= cur; ++j) row_ptr[j] = e;
    if (e == E - 1) {
        for (int j = cur + 1; j <= N; ++j) row_ptr[j] = E;
    }
}

__device__ __forceinline__ unsigned f2bf_rne(float x) {
    unsigned u = __float_as_uint(x);
    return (u + 0x7fffu + ((u >> 16) & 1u)) >> 16;  // round-nearest-even bf16
}

// KV[s][d] = (bf16(V[s][d]) << 16) | bf16(K[s][d]); one 128 B row per node
// carries both K and V (halves random-gather lines AND bytes per edge).
__global__ void repack_kv_kernel(const float* __restrict__ K,
                                 const float* __restrict__ V,
                                 unsigned* __restrict__ KV, int total) {
    int i = blockIdx.x * blockDim.x + threadIdx.x;
    if (i >= total) return;
    KV[i] = (f2bf_rne(V[i]) << 16) | f2bf_rne(K[i]);
}

// One 64-lane wave handles NODES_PER_WAVE consecutive nodes. Lane = (g, c):
// g = lane>>3 is one of 8 edge slots, c = lane&7 is a 4-dim chunk. One
// dwordx4 wave load = 8 full 128 B KV rows. 16 edges per iteration. Dot
// reduce = xor(1,2,4). No running max (scores ~ N(0,1/32), exp safe). No LDS.
// W_o column + bias loaded once per wave (amortized over the node loop).
__global__ __launch_bounds__(256) void gat_node_kv_kernel(
    const float* __restrict__ X, const uint4* __restrict__ KV,
    const float* __restrict__ Wo, const float* __restrict__ bo,
    const int* __restrict__ src, const int* __restrict__ row_ptr,
    float* __restrict__ out, int N) {

    const int tid  = threadIdx.x;
    const int wave = tid >> 6;
    const int lane = tid & 63;
    const int g    = lane >> 3;   // edge slot 0..7
    const int c    = lane & 7;    // dim chunk 0..7
    const int j    = lane & 31;   // output column
    const int half = lane >> 5;

    const int n0 = (blockIdx.x * 4 + wave) * NODES_PER_WAVE;
    if (n0 >= N) return;

    // per-wave W_o column j (32 regs) + bias — amortized over NODES_PER_WAVE
    float wcol[32];
#pragma unroll
    for (int k = 0; k < 32; ++k) wcol[k] = Wo[k * OUT_DIM + j];
    const float bj = bo[j];

    const float4* X4 = (const float4*)X;

    for (int i = 0; i < NODES_PER_WAVE; ++i) {
        const int n = n0 + i;
        if (n >= N) break;
        const int begin = row_ptr[n];
        const int end   = row_ptr[n + 1];

        float4 q4 = X4[n * 8 + c];      // dims [4c, 4c+4) of Q row
        q4.x *= 0.03125f; q4.y *= 0.03125f;  // fold 1/dk into q
        q4.z *= 0.03125f; q4.w *= 0.03125f;

        float  l   = 0.0f;
        float4 acc = make_float4(0.0f, 0.0f, 0.0f, 0.0f);

        for (int e0 = begin; e0 < end; e0 += 16) {
            const int  ea = e0 + g;
            const int  eb = ea + 8;
            const int  sa = src[min(ea, end - 1)];
            const int  sb = src[min(eb, end - 1)];
            // 2 wave-wide dwordx4 gathers = 16 KV rows (one line per edge)
            const uint4 A = KV[sa * 8 + c];
            const uint4 B = KV[sb * 8 + c];

            // K parts: low 16 bits -> float via <<16
            const float ka0 = __uint_as_float(A.x << 16);
            const float ka1 = __uint_as_float(A.y << 16);
            const float ka2 = __uint_as_float(A.z << 16);
            const float ka3 = __uint_as_float(A.w << 16);
            const float kb0 = __uint_as_float(B.x << 16);
            const float kb1 = __uint_as_float(B.y << 16);
            const float kb2 = __uint_as_float(B.z << 16);
            const float kb3 = __uint_as_float(B.w << 16);

            float pa = fmaf(ka0, q4.x, fmaf(ka1, q4.y, fmaf(ka2, q4.z, ka3 * q4.w)));
            float pb = fmaf(kb0, q4.x, fmaf(kb1, q4.y, fmaf(kb2, q4.z, kb3 * q4.w)));
            pa += __shfl_xor(pa, 1);  pb += __shfl_xor(pb, 1);
            pa += __shfl_xor(pa, 2);  pb += __shfl_xor(pb, 2);
            pa += __shfl_xor(pa, 4);  pb += __shfl_xor(pb, 4);

            const float wa = (ea < end) ? __expf(pa) : 0.0f;
            const float wb = (eb < end) ? __expf(pb) : 0.0f;
            l += wa + wb;

            // V parts: high 16 bits
            acc.x = fmaf(wa, __uint_as_float(A.x & 0xffff0000u), acc.x);
            acc.y = fmaf(wa, __uint_as_float(A.y & 0xffff0000u), acc.y);
            acc.z = fmaf(wa, __uint_as_float(A.z & 0xffff0000u), acc.z);
            acc.w = fmaf(wa, __uint_as_float(A.w & 0xffff0000u), acc.w);
            acc.x = fmaf(wb, __uint_as_float(B.x & 0xffff0000u), acc.x);
            acc.y = fmaf(wb, __uint_as_float(B.y & 0xffff0000u), acc.y);
            acc.z = fmaf(wb, __uint_as_float(B.z & 0xffff0000u), acc.z);
            acc.w = fmaf(wb, __uint_as_float(B.w & 0xffff0000u), acc.w);
        }

        // reduce across the 8 edge-slot groups (lane bits 3,4,5)
#pragma unroll
        for (int m = 8; m <= 32; m <<= 1) {
            l     += __shfl_xor(l, m);
            acc.x += __shfl_xor(acc.x, m);
            acc.y += __shfl_xor(acc.y, m);
            acc.z += __shfl_xor(acc.z, m);
            acc.w += __shfl_xor(acc.w, m);
        }

        const float inv = (end > begin) ? (1.0f / l) : 0.0f;

        // out[n][j] = bo[j] + inv * sum_k acc_row[k] * W[k][j]
        // acc_row[k] in lane k>>2 (constant in unrolled loop), comp k&3.
        float ag[4] = {acc.x, acc.y, acc.z, acc.w};
        float s = 0.0f;
#pragma unroll
        for (int k = 0; k < 32; ++k) {
            const float a = __int_as_float(
                __builtin_amdgcn_readlane(__float_as_int(ag[k & 3]), k >> 2));
            s = fmaf(a, wcol[k], s);
        }
        if (half == 0) {
            out[n * OUT_DIM + j] = fmaf(s, inv, bj);
        }
    }
}

// ---- fallback (R4-proven fp32 path, used only if ws too small for KV) ----
__global__ __launch_bounds__(256) void gat_node_f32_kernel(
    const float* __restrict__ X, const float* __restrict__ Km,
    const float* __restrict__ Vm, const float* __restrict__ Wo,
    const float* __restrict__ bo, const int* __restrict__ src,
    const int* __restrict__ row_ptr, float* __restrict__ out, int N) {
    const int tid  = threadIdx.x;
    const int wave = tid >> 6;
    const int lane = tid & 63;
    const int g    = lane >> 3;
    const int c    = lane & 7;
    const int j    = lane & 31;
    const int half = lane >> 5;
    const int n = blockIdx.x * 4 + wave;
    if (n >= N) return;
    const int begin = row_ptr[n];
    const int end   = row_ptr[n + 1];
    const float4* X4 = (const float4*)X;
    const float4* K4 = (const float4*)Km;
    const float4* V4 = (const float4*)Vm;
    const float4 q4 = X4[n * 8 + c];
    float  l   = 0.0f;
    float4 acc = make_float4(0.0f, 0.0f, 0.0f, 0.0f);
    for (int e0 = begin; e0 < end; e0 += 16) {
        const int  ea = e0 + g;
        const int  eb = ea + 8;
        const bool va = ea < end;
        const bool vb = eb < end;
        const int sa = src[min(ea, end - 1)];
        const int sb = src[min(eb, end - 1)];
        const float4 ka  = K4[sa * 8 + c];
        const float4 kb  = K4[sb * 8 + c];
        const float4 vva = V4[sa * 8 + c];
        const float4 vvb = V4[sb * 8 + c];
        float pa = fmaf(ka.x, q4.x, fmaf(ka.y, q4.y, fmaf(ka.z, q4.z, ka.w * q4.w)));
        float pb = fmaf(kb.x, q4.x, fmaf(kb.y, q4.y, fmaf(kb.z, q4.z, kb.w * q4.w)));
        pa += __shfl_xor(pa, 1);  pb += __shfl_xor(pb, 1);
        pa += __shfl_xor(pa, 2);  pb += __shfl_xor(pb, 2);
        pa += __shfl_xor(pa, 4);  pb += __shfl_xor(pb, 4);
        const float wa = va ? __expf(pa * 0.03125f) : 0.0f;
        const float wb = vb ? __expf(pb * 0.03125f) : 0.0f;
        l += wa + wb;
        acc.x = fmaf(wa, vva.x, acc.x);  acc.y = fmaf(wa, vva.y, acc.y);
        acc.z = fmaf(wa, vva.z, acc.z);  acc.w = fmaf(wa, vva.w, acc.w);
        acc.x = fmaf(wb, vvb.x, acc.x);  acc.y = fmaf(wb, vvb.y, acc.y);
        acc.z = fmaf(wb, vvb.z, acc.z);  acc.w = fmaf(wb, vvb.w, acc.w);
    }
#pragma unroll
    for (int m = 8; m <= 32; m <<= 1) {
        l     += __shfl_xor(l, m);
        acc.x += __shfl_xor(acc.x, m);
        acc.y += __shfl_xor(acc.y, m);
        acc.z += __shfl_xor(acc.z, m);
        acc.w += __shfl_xor(acc.w, m);
    }
    const float inv = (end > begin) ? (1.0f / l) : 0.0f;
    float ag[4] = {acc.x, acc.y, acc.z, acc.w};
    float s = 0.0f;
#pragma unroll
    for (int k = 0; k < 32; ++k) {
        const float a = __int_as_float(
            __builtin_amdgcn_readlane(__float_as_int(ag[k & 3]), k >> 2));
        s = fmaf(a, Wo[k * OUT_DIM + j], s);
    }
    if (half == 0) {
        out[n * OUT_DIM + j] = fmaf(s, inv, bo[j]);
    }
}

extern "C" void kernel_launch(void* const* d_in, const int* in_sizes, int n_in,
                              void* d_out, int out_size, void* d_ws, size_t ws_size,
                              hipStream_t stream) {
    const float* X  = (const float*)d_in[0];
    const float* Km = (const float*)d_in[1];
    const float* Vm = (const float*)d_in[2];
    const float* Wo = (const float*)d_in[3];
    const float* bo = (const float*)d_in[4];
    const int* src  = (const int*)d_in[5];
    const int* dst  = (const int*)d_in[6];

    const int N = in_sizes[0] / DK;
    const int E = in_sizes[5];

    int* row_ptr = (int*)d_ws;                              // (N+1) ints
    const size_t kv_off = (((size_t)(N + 1) * 4) + 127) & ~(size_t)127;
    unsigned* KV = (unsigned*)((char*)d_ws + kv_off);       // N*DK uint32
    const size_t need = kv_off + (size_t)N * DK * 4;
    float* out = (float*)d_out;

    const int tb = 256;
    build_row_ptr_kernel<<<(E + tb - 1) / tb, tb, 0, stream>>>(dst, E, N, row_ptr);

    if (ws_size >= need) {
        const int total = N * DK;
        repack_kv_kernel<<<(total + tb - 1) / tb, tb, 0, stream>>>(Km, Vm, KV, total);
        const int waves = (N + NODES_PER_WAVE - 1) / NODES_PER_WAVE;
        const int grid  = (waves + 3) / 4;                  // 4 waves per block
        gat_node_kv_kernel<<<grid, 256, 0, stream>>>(X, (const uint4*)KV, Wo, bo,
                                                     src, row_ptr, out, N);
    } else {
        const int grid = (N + 3) / 4;
        gat_node_f32_kernel<<<grid, 256, 0, stream>>>(X, Km, Vm, Wo, bo,
                                                      src, row_ptr, out, N);
    }
}

// Round 6
// 151.932 us; speedup vs baseline: 1.0389x; 1.0389x over previous
//
#include <hip/hip_runtime.h>
#include <math.h>

#define DK 32
#define OUT_DIM 32

typedef float  f32x4  __attribute__((ext_vector_type(4)));
typedef short  bf16x8 __attribute__((ext_vector_type(8)));

// Fill row_ptr[0..N] such that row_ptr[n] = first edge index with dst >= n.
__global__ void build_row_ptr_kernel(const int* __restrict__ dst, int E, int N,
                                     int* __restrict__ row_ptr) {
    int e = blockIdx.x * blockDim.x + threadIdx.x;
    if (e >= E) return;
    int cur  = dst[e];
    int prev = (e == 0) ? -1 : dst[e - 1];
    for (int j = prev + 1; j <= cur; ++j) row_ptr[j] = e;
    if (e == E - 1) {
        for (int j = cur + 1; j <= N; ++j) row_ptr[j] = E;
    }
}

__device__ __forceinline__ unsigned f2bf_rne(float x) {
    unsigned u = __float_as_uint(x);
    return (u + 0x7fffu + ((u >> 16) & 1u)) >> 16;  // round-nearest-even bf16
}

// KV[s][d] = (bf16(V[s][d]) << 16) | bf16(K[s][d]); one 128 B row per node
// carries both K and V (one random line per edge gather).
__global__ void repack_kv_kernel(const float* __restrict__ K,
                                 const float* __restrict__ V,
                                 unsigned* __restrict__ KV, int total) {
    int i = blockIdx.x * blockDim.x + threadIdx.x;
    if (i >= total) return;
    KV[i] = (f2bf_rne(V[i]) << 16) | f2bf_rne(K[i]);
}

// One 64-lane wave owns 16 consecutive nodes. Edge loop identical to the
// proven R5 shape: lane = (g = edge slot 0..7, c = dim chunk 0..7), 16 edges
// per iteration, one 128 B KV line per edge, dot reduce xor(1,2,4), no
// running max (scores ~ N(0,1/32), exp safe).
//
// NEW: per-node epilogue shrinks to one xor(8) merge (8 -> 4 partials) +
// l-reduce + normalize + bf16-pack + 2 LDS writes. The 4-partial reduction
// AND the W_o projection are then done together by 8 MFMAs per wave:
//   out(16x32) = part(16x[4x32]) @ Wrep([4x32]x32) + b
// where Wrep is W_o replicated across the 4 partial groups (so the B
// fragment is identical for all K-chunks). Per-wave LDS region -> no
// __syncthreads anywhere.
__global__ __launch_bounds__(256) void gat_fused_kernel(
    const float* __restrict__ X, const uint4* __restrict__ KV,
    const float* __restrict__ Wo, const float* __restrict__ bo,
    const int* __restrict__ src, const int* __restrict__ row_ptr,
    float* __restrict__ out, int N) {

    // per-wave A-tile: 16 rows x 17 uint4 (16 data + 1 pad). Row = 272 B ->
    // 16 B-aligned ds_read_b128, bank stride 68 dwords = 4 mod 32 (2-way max).
    __shared__ uint4 s_part[4][16 * 17];

    const int tid  = threadIdx.x;
    const int wave = tid >> 6;
    const int lane = tid & 63;
    const int g    = lane >> 3;   // edge slot 0..7
    const int c    = lane & 7;    // dim chunk 0..7
    const int quad = lane >> 4;   // MFMA quad 0..3
    const int col  = lane & 15;   // MFMA col / A-row index

    const int n0 = (blockIdx.x * 4 + wave) * 16;
    if (n0 >= N) return;

    // B fragments (W_o, bf16) for the two 16-col output tiles; identical for
    // every K-chunk because W is replicated across partial groups. Loaded
    // once per wave (4 KB table, L1-resident). Layout: B[k=quad*8+j][n].
    union BF { bf16x8 v; unsigned short u[8]; };
    BF bf0, bf1;
#pragma unroll
    for (int j2 = 0; j2 < 8; ++j2) {
        bf0.u[j2] = (unsigned short)f2bf_rne(Wo[(quad * 8 + j2) * OUT_DIM + col]);
        bf1.u[j2] = (unsigned short)f2bf_rne(Wo[(quad * 8 + j2) * OUT_DIM + 16 + col]);
    }
    const float bias0 = bo[col];
    const float bias1 = bo[16 + col];

    const float4* X4 = (const float4*)X;
    unsigned* part32 = (unsigned*)&s_part[wave][0];

    for (int i = 0; i < 16; ++i) {
        const int n = n0 + i;
        float  l   = 0.0f;
        float4 acc = make_float4(0.0f, 0.0f, 0.0f, 0.0f);
        int begin = 0, end = 0;

        if (n < N) {
            begin = row_ptr[n];
            end   = row_ptr[n + 1];

            float4 q4 = X4[n * 8 + c];          // dims [4c,4c+4) of Q row
            q4.x *= 0.03125f; q4.y *= 0.03125f; // fold 1/dk into q
            q4.z *= 0.03125f; q4.w *= 0.03125f;

            for (int e0 = begin; e0 < end; e0 += 16) {
                const int ea = e0 + g;
                const int eb = ea + 8;
                const int sa = src[min(ea, end - 1)];
                const int sb = src[min(eb, end - 1)];
                const uint4 A = KV[sa * 8 + c];   // 16 KV rows per 2 loads
                const uint4 B = KV[sb * 8 + c];

                const float ka0 = __uint_as_float(A.x << 16);
                const float ka1 = __uint_as_float(A.y << 16);
                const float ka2 = __uint_as_float(A.z << 16);
                const float ka3 = __uint_as_float(A.w << 16);
                const float kb0 = __uint_as_float(B.x << 16);
                const float kb1 = __uint_as_float(B.y << 16);
                const float kb2 = __uint_as_float(B.z << 16);
                const float kb3 = __uint_as_float(B.w << 16);

                float pa = fmaf(ka0, q4.x, fmaf(ka1, q4.y, fmaf(ka2, q4.z, ka3 * q4.w)));
                float pb = fmaf(kb0, q4.x, fmaf(kb1, q4.y, fmaf(kb2, q4.z, kb3 * q4.w)));
                pa += __shfl_xor(pa, 1);  pb += __shfl_xor(pb, 1);
                pa += __shfl_xor(pa, 2);  pb += __shfl_xor(pb, 2);
                pa += __shfl_xor(pa, 4);  pb += __shfl_xor(pb, 4);

                const float wa = (ea < end) ? __expf(pa) : 0.0f;
                const float wb = (eb < end) ? __expf(pb) : 0.0f;
                l += wa + wb;

                acc.x = fmaf(wa, __uint_as_float(A.x & 0xffff0000u), acc.x);
                acc.y = fmaf(wa, __uint_as_float(A.y & 0xffff0000u), acc.y);
                acc.z = fmaf(wa, __uint_as_float(A.z & 0xffff0000u), acc.z);
                acc.w = fmaf(wa, __uint_as_float(A.w & 0xffff0000u), acc.w);
                acc.x = fmaf(wb, __uint_as_float(B.x & 0xffff0000u), acc.x);
                acc.y = fmaf(wb, __uint_as_float(B.y & 0xffff0000u), acc.y);
                acc.z = fmaf(wb, __uint_as_float(B.z & 0xffff0000u), acc.z);
                acc.w = fmaf(wb, __uint_as_float(B.w & 0xffff0000u), acc.w);
            }
        }

        // merge group pairs: 8 -> 4 partials (lane L with L^8)
        l     += __shfl_xor(l, 8);
        acc.x += __shfl_xor(acc.x, 8);
        acc.y += __shfl_xor(acc.y, 8);
        acc.z += __shfl_xor(acc.z, 8);
        acc.w += __shfl_xor(acc.w, 8);
        // l needs the full reduction for the softmax denominator
        l += __shfl_xor(l, 16);
        l += __shfl_xor(l, 32);

        const float inv = (end > begin) ? (1.0f / l) : 0.0f;
        acc.x *= inv; acc.y *= inv; acc.z *= inv; acc.w *= inv;

        // even groups hold the pair sums; write partial p = g>>1, dims 4c..4c+3
        if ((g & 1) == 0) {
            const int p   = g >> 1;
            const int off = i * 68 + p * 16 + c * 2;  // uint32 units, 8B-aligned
            part32[off]     = f2bf_rne(acc.x) | (f2bf_rne(acc.y) << 16);
            part32[off + 1] = f2bf_rne(acc.z) | (f2bf_rne(acc.w) << 16);
        }
    }

    // Projection + partial-group reduction in one MFMA chain.
    // A[m=col][k] with k = p*32 + dim; chunk cc = partial p = cc.
    union AF { uint4 u; bf16x8 v; };
    f32x4 C0 = {bias0, bias0, bias0, bias0};
    f32x4 C1 = {bias1, bias1, bias1, bias1};
#pragma unroll
    for (int cc = 0; cc < 4; ++cc) {
        AF a;
        a.u = s_part[wave][col * 17 + cc * 4 + quad];  // ds_read_b128
        C0 = __builtin_amdgcn_mfma_f32_16x16x32_bf16(a.v, bf0.v, C0, 0, 0, 0);
        C1 = __builtin_amdgcn_mfma_f32_16x16x32_bf16(a.v, bf1.v, C1, 0, 0, 0);
    }

    // C/D layout: col = lane&15, row = quad*4 + reg  (verified mapping)
#pragma unroll
    for (int r = 0; r < 4; ++r) {
        const int n = n0 + quad * 4 + r;
        if (n < N) {
            out[n * OUT_DIM + col]      = C0[r];
            out[n * OUT_DIM + 16 + col] = C1[r];
        }
    }
}

// ---- fallback (R4-proven fp32 path, used only if ws too small for KV) ----
__global__ __launch_bounds__(256) void gat_node_f32_kernel(
    const float* __restrict__ X, const float* __restrict__ Km,
    const float* __restrict__ Vm, const float* __restrict__ Wo,
    const float* __restrict__ bo, const int* __restrict__ src,
    const int* __restrict__ row_ptr, float* __restrict__ out, int N) {
    const int tid  = threadIdx.x;
    const int wave = tid >> 6;
    const int lane = tid & 63;
    const int g    = lane >> 3;
    const int c    = lane & 7;
    const int j    = lane & 31;
    const int half = lane >> 5;
    const int n = blockIdx.x * 4 + wave;
    if (n >= N) return;
    const int begin = row_ptr[n];
    const int end   = row_ptr[n + 1];
    const float4* X4 = (const float4*)X;
    const float4* K4 = (const float4*)Km;
    const float4* V4 = (const float4*)Vm;
    const float4 q4 = X4[n * 8 + c];
    float  l   = 0.0f;
    float4 acc = make_float4(0.0f, 0.0f, 0.0f, 0.0f);
    for (int e0 = begin; e0 < end; e0 += 16) {
        const int  ea = e0 + g;
        const int  eb = ea + 8;
        const bool va = ea < end;
        const bool vb = eb < end;
        const int sa = src[min(ea, end - 1)];
        const int sb = src[min(eb, end - 1)];
        const float4 ka  = K4[sa * 8 + c];
        const float4 kb  = K4[sb * 8 + c];
        const float4 vva = V4[sa * 8 + c];
        const float4 vvb = V4[sb * 8 + c];
        float pa = fmaf(ka.x, q4.x, fmaf(ka.y, q4.y, fmaf(ka.z, q4.z, ka.w * q4.w)));
        float pb = fmaf(kb.x, q4.x, fmaf(kb.y, q4.y, fmaf(kb.z, q4.z, kb.w * q4.w)));
        pa += __shfl_xor(pa, 1);  pb += __shfl_xor(pb, 1);
        pa += __shfl_xor(pa, 2);  pb += __shfl_xor(pb, 2);
        pa += __shfl_xor(pa, 4);  pb += __shfl_xor(pb, 4);
        const float wa = va ? __expf(pa * 0.03125f) : 0.0f;
        const float wb = vb ? __expf(pb * 0.03125f) : 0.0f;
        l += wa + wb;
        acc.x = fmaf(wa, vva.x, acc.x);  acc.y = fmaf(wa, vva.y, acc.y);
        acc.z = fmaf(wa, vva.z, acc.z);  acc.w = fmaf(wa, vva.w, acc.w);
        acc.x = fmaf(wb, vvb.x, acc.x);  acc.y = fmaf(wb, vvb.y, acc.y);
        acc.z = fmaf(wb, vvb.z, acc.z);  acc.w = fmaf(wb, vvb.w, acc.w);
    }
#pragma unroll
    for (int m = 8; m <= 32; m <<= 1) {
        l     += __shfl_xor(l, m);
        acc.x += __shfl_xor(acc.x, m);
        acc.y += __shfl_xor(acc.y, m);
        acc.z += __shfl_xor(acc.z, m);
        acc.w += __shfl_xor(acc.w, m);
    }
    const float inv = (end > begin) ? (1.0f / l) : 0.0f;
    float ag[4] = {acc.x, acc.y, acc.z, acc.w};
    float s = 0.0f;
#pragma unroll
    for (int k = 0; k < 32; ++k) {
        const float a = __int_as_float(
            __builtin_amdgcn_readlane(__float_as_int(ag[k & 3]), k >> 2));
        s = fmaf(a, Wo[k * OUT_DIM + j], s);
    }
    if (half == 0) {
        out[n * OUT_DIM + j] = fmaf(s, inv, bo[j]);
    }
}

extern "C" void kernel_launch(void* const* d_in, const int* in_sizes, int n_in,
                              void* d_out, int out_size, void* d_ws, size_t ws_size,
                              hipStream_t stream) {
    const float* X  = (const float*)d_in[0];
    const float* Km = (const float*)d_in[1];
    const float* Vm = (const float*)d_in[2];
    const float* Wo = (const float*)d_in[3];
    const float* bo = (const float*)d_in[4];
    const int* src  = (const int*)d_in[5];
    const int* dst  = (const int*)d_in[6];

    const int N = in_sizes[0] / DK;
    const int E = in_sizes[5];

    int* row_ptr = (int*)d_ws;                              // (N+1) ints
    const size_t kv_off = (((size_t)(N + 1) * 4) + 127) & ~(size_t)127;
    unsigned* KV = (unsigned*)((char*)d_ws + kv_off);       // N*DK uint32
    const size_t need = kv_off + (size_t)N * DK * 4;
    float* out = (float*)d_out;

    const int tb = 256;
    build_row_ptr_kernel<<<(E + tb - 1) / tb, tb, 0, stream>>>(dst, E, N, row_ptr);

    if (ws_size >= need) {
        const int total = N * DK;
        repack_kv_kernel<<<(total + tb - 1) / tb, tb, 0, stream>>>(Km, Vm, KV, total);
        const int waves = (N + 15) / 16;                    // 16 nodes per wave
        const int grid  = (waves + 3) / 4;                  // 4 waves per block
        gat_fused_kernel<<<grid, 256, 0, stream>>>(X, (const uint4*)KV, Wo, bo,
                                                   src, row_ptr, out, N);
    } else {
        const int grid = (N + 3) / 4;
        gat_node_f32_kernel<<<grid, 256, 0, stream>>>(X, Km, Vm, Wo, bo,
                                                      src, row_ptr, out, N);
    }
}